// Round 3
// baseline (421.833 us; speedup 1.0000x reference)
//
#include <hip/hip_runtime.h>

#define BATCH 32
#define I_TOT 4096
#define N_CAP 16
#define K_DIM 128
#define RCHUNK 128
#define TILE 64
#define NCHUNK 32        // I_TOT / RCHUNK

// ws layout (floats):
//   w_o: [B][16][128]   off 0      (65536)
//   sp:  [B][32][2048]  off 65536  (2097152)   -- routing partials
//        (colsum partials [B][32][128] alias the sp region; consumed by
//         update mode 0 before routing pass 1 overwrites it)
#define WS_WO 0
#define WS_SP 65536

// ---------------------------------------------------------------------------
// K1: colsum partials. grid (32, B), block 256. No zeroing needed.
__global__ __launch_bounds__(256) void colsum_kernel(const float* __restrict__ u,
                                                     float* __restrict__ ws) {
    const int b = blockIdx.y, chunk = blockIdx.x, t = threadIdx.x;
    const int k4 = t & 31, rg = t >> 5;
    const float4* up = (const float4*)u + ((size_t)b * I_TOT + chunk * RCHUNK + rg) * 32 + k4;
    float4 acc = {0.f, 0.f, 0.f, 0.f};
    #pragma unroll
    for (int i = 0; i < 16; i++) {
        float4 v = up[(size_t)i * 256];   // 8 rows * 32 float4
        acc.x += v.x; acc.y += v.y; acc.z += v.z; acc.w += v.w;
    }
    __shared__ __align__(16) float4 red[8][32];
    red[rg][k4] = acc;
    __syncthreads();
    if (t < 32) {
        float4 s = red[0][t];
        #pragma unroll
        for (int r = 1; r < 8; r++) {
            float4 v = red[r][t];
            s.x += v.x; s.y += v.y; s.z += v.z; s.w += v.w;
        }
        ((float4*)(ws + WS_SP + ((size_t)b * NCHUNK + chunk) * K_DIM))[t] = s;
    }
}

// ---------------------------------------------------------------------------
// K2: update. mode 0: o from colsum partials; 1: o from sp, l2norm+w_o; 2: squash->out.
__global__ __launch_bounds__(256) void update_kernel(const float* __restrict__ W,
                                                     float* __restrict__ ws,
                                                     float* __restrict__ out,
                                                     int mode) {
    const int b = blockIdx.x, t = threadIdx.x;
    const int n = t >> 4, d = t & 15;

    __shared__ float src_s[N_CAP][K_DIM + 2];
    __shared__ float o_s[N_CAP][16];

    if (mode == 0) {
        const float* sp = ws + WS_SP + (size_t)b * NCHUNK * K_DIM;
        int k = t & 127, half = t >> 7;
        float a = 0.f;
        #pragma unroll
        for (int c = 0; c < 16; c++) a += sp[(size_t)(half * 16 + c) * K_DIM + k];
        __shared__ float cred[2][128];
        cred[half][k] = a;
        __syncthreads();
        if (t < 128) src_s[0][t] = (cred[0][t] + cred[1][t]) * (1.f / 16.f);
        __syncthreads();
    } else {
        const float* sp = ws + WS_SP + (size_t)b * NCHUNK * 2048;
        #pragma unroll
        for (int j = 0; j < 8; j++) {
            int idx = t + j * 256;
            float a = 0.f;
            #pragma unroll 8
            for (int ch = 0; ch < NCHUNK; ch++) a += sp[(size_t)ch * 2048 + idx];
            src_s[idx >> 7][idx & 127] = a;
        }
        __syncthreads();
    }

    const float* srow = (mode == 0) ? src_s[0] : src_s[n];
    float o = 0.f;
    #pragma unroll 8
    for (int k = 0; k < K_DIM; k++) o += srow[k] * W[k * 256 + t];

    o_s[n][d] = o;
    __syncthreads();

    if (mode == 2) {
        float ss = 1e-7f;  // EPS
        #pragma unroll
        for (int j = 0; j < 16; j++) { float v = o_s[n][j]; ss += v * v; }
        float scale = sqrtf(ss) / (0.5f + ss);
        out[b * 256 + t] = scale * o;
        return;
    }

    float ss = 0.f;
    #pragma unroll
    for (int j = 0; j < 16; j++) { float v = o_s[n][j]; ss += v * v; }
    float on = o * rsqrtf(fmaxf(ss, 1e-12f));
    __syncthreads();   // done reading src_s; reuse it as w_o staging

    // w_o[n][k] = sum_d W[k][n*16+d] * on(d)  -- coalesced W pass + 16-lane reduce
    for (int k = 0; k < K_DIM; k++) {
        float p = W[k * 256 + t] * on;
        p += __shfl_xor(p, 1); p += __shfl_xor(p, 2);
        p += __shfl_xor(p, 4); p += __shfl_xor(p, 8);
        if (d == 0) src_s[n][k] = p;
    }
    __syncthreads();
    float* wo = ws + WS_WO + (size_t)b * 2048;
    #pragma unroll
    for (int j = 0; j < 8; j++) {
        int idx = t + j * 256;
        wo[idx] = src_s[idx >> 7][idx & 127];
    }
}

// ---------------------------------------------------------------------------
// K3: routing pass. grid (32, B), block 256. u staged once in LDS (swizzled),
// two 64-row sub-tiles; phase1: 4 rows/thread x 8-float k-seg; phase2: k-parallel.
__global__ __launch_bounds__(256) void routing_kernel(const float* __restrict__ u,
                                                      float* __restrict__ ws) {
    const int b = blockIdx.y, chunk = blockIdx.x, t = threadIdx.x;

    __shared__ __align__(16) float u_s[TILE * K_DIM];      // 32 KB, XOR-swizzled
    __shared__ __align__(16) float wo_s[N_CAP][K_DIM];     // 8 KB
    __shared__ __align__(16) float c_s[TILE][20];          // 5 KB (pad 20 keeps 16B align)

    {
        const float4* wg = (const float4*)(ws + WS_WO + (size_t)b * 2048);
        ((float4*)wo_s)[t * 2]     = wg[t * 2];
        ((float4*)wo_s)[t * 2 + 1] = wg[t * 2 + 1];
    }

    const int s16 = t & 15, rg = t >> 4;      // phase-1 mapping
    const int k2 = t & 63, cg = t >> 6;       // phase-2 mapping
    float2 a0 = {0.f,0.f}, a1 = {0.f,0.f}, a2 = {0.f,0.f}, a3 = {0.f,0.f};

    for (int tile = 0; tile < 2; tile++) {
        // ---- stage 64 rows, swizzle float4-block j -> j ^ (r&7) ----
        const float4* gsrc = (const float4*)(u + ((size_t)b * I_TOT + chunk * RCHUNK + tile * TILE) * K_DIM);
        #pragma unroll
        for (int m = 0; m < 8; m++) {
            int f = m * 256 + t;             // float4 index 0..2047
            int r = f >> 5, j = f & 31;
            float4 v = gsrc[f];
            *(float4*)&u_s[r * K_DIM + ((j ^ (r & 7)) << 2)] = v;
        }
        __syncthreads();

        // ---- phase 1: logits for rows rg*4..rg*4+3, k-segment s16*8..+7 ----
        float4 fr[4][2];
        #pragma unroll
        for (int e = 0; e < 4; e++) {
            int r = rg * 4 + e;
            #pragma unroll
            for (int h = 0; h < 2; h++)
                fr[e][h] = *(const float4*)&u_s[r * K_DIM + (((s16 * 2 + h) ^ (r & 7)) << 2)];
        }
        float lg[4][16];
        #pragma unroll
        for (int e = 0; e < 4; e++)
            #pragma unroll
            for (int n = 0; n < 16; n++) lg[e][n] = 0.f;

        #pragma unroll
        for (int n = 0; n < N_CAP; n++) {
            float4 w0 = *(const float4*)&wo_s[n][s16 * 8];
            float4 w1 = *(const float4*)&wo_s[n][s16 * 8 + 4];
            #pragma unroll
            for (int e = 0; e < 4; e++) {
                lg[e][n] += fr[e][0].x * w0.x + fr[e][0].y * w0.y
                          + fr[e][0].z * w0.z + fr[e][0].w * w0.w
                          + fr[e][1].x * w1.x + fr[e][1].y * w1.y
                          + fr[e][1].z * w1.z + fr[e][1].w * w1.w;
            }
        }
        // reduce partial logits across the 16 k-segment lanes
        #pragma unroll
        for (int e = 0; e < 4; e++) {
            #pragma unroll
            for (int n = 0; n < 16; n++) {
                float v = lg[e][n];
                v += __shfl_xor(v, 1); v += __shfl_xor(v, 2);
                v += __shfl_xor(v, 4); v += __shfl_xor(v, 8);
                lg[e][n] = v;
            }
        }
        // each lane: softmax of row (rg*4 + s16>>2), writes n-range (s16&3)*4..+3
        const int e_sel = s16 >> 2;
        float lr[16];
        #pragma unroll
        for (int n = 0; n < 16; n++) {
            float v01 = (e_sel & 1) ? lg[1][n] : lg[0][n];
            float v23 = (e_sel & 1) ? lg[3][n] : lg[2][n];
            lr[n] = (e_sel & 2) ? v23 : v01;
        }
        float mx = lr[0];
        #pragma unroll
        for (int n = 1; n < 16; n++) mx = fmaxf(mx, lr[n]);
        float ex[16]; float sum = 0.f;
        #pragma unroll
        for (int n = 0; n < 16; n++) { ex[n] = __expf(lr[n] - mx); sum += ex[n]; }
        float inv = 1.f / sum;
        const int row = rg * 4 + e_sel;
        const int nb = (s16 & 3) * 4;
        #pragma unroll
        for (int q = 0; q < 4; q++) {
            float v01 = (s16 & 1) ? ex[4 + q]  : ex[q];
            float v23 = (s16 & 1) ? ex[12 + q] : ex[8 + q];
            float v = (s16 & 2) ? v23 : v01;
            c_s[row][nb + q] = v * inv;
        }
        __syncthreads();

        // ---- phase 2: s[cap][k] += sum_i c[i][cap] * u[i][k] ----
        #pragma unroll 4
        for (int i = 0; i < TILE; i++) {
            float2 u2 = *(const float2*)&u_s[i * K_DIM + (((k2 >> 1) ^ (i & 7)) << 2) + ((k2 & 1) << 1)];
            float4 c4 = *(const float4*)&c_s[i][cg * 4];
            a0.x += u2.x * c4.x; a0.y += u2.y * c4.x;
            a1.x += u2.x * c4.y; a1.y += u2.y * c4.y;
            a2.x += u2.x * c4.z; a2.y += u2.y * c4.z;
            a3.x += u2.x * c4.w; a3.y += u2.y * c4.w;
        }
        __syncthreads();   // u_s/c_s reused by next tile
    }

    float* sp = ws + WS_SP + ((size_t)b * NCHUNK + chunk) * 2048;
    const int kk = k2 * 2;
    *(float2*)&sp[(cg * 4 + 0) * K_DIM + kk] = a0;
    *(float2*)&sp[(cg * 4 + 1) * K_DIM + kk] = a1;
    *(float2*)&sp[(cg * 4 + 2) * K_DIM + kk] = a2;
    *(float2*)&sp[(cg * 4 + 3) * K_DIM + kk] = a3;
}

// ---------------------------------------------------------------------------
extern "C" void kernel_launch(void* const* d_in, const int* in_sizes, int n_in,
                              void* d_out, int out_size, void* d_ws, size_t ws_size,
                              hipStream_t stream) {
    const float* u = (const float*)d_in[0];   // (32, 4096, 128) f32
    const float* W = (const float*)d_in[1];   // (128, 256) f32
    float* out = (float*)d_out;               // (32, 16, 16) f32
    float* ws = (float*)d_ws;

    colsum_kernel<<<dim3(NCHUNK, BATCH), 256, 0, stream>>>(u, ws);
    update_kernel<<<BATCH, 256, 0, stream>>>(W, ws, out, 0);

    for (int pass = 0; pass < 3; pass++) {
        routing_kernel<<<dim3(NCHUNK, BATCH), 256, 0, stream>>>(u, ws);
        update_kernel<<<BATCH, 256, 0, stream>>>(W, ws, out, pass == 2 ? 2 : 1);
    }
}

// Round 4
// 217.200 us; speedup vs baseline: 1.9421x; 1.9421x over previous
//
#include <hip/hip_runtime.h>

#define BATCH 32
#define I_TOT 4096
#define N_CAP 16
#define K_DIM 128
#define RCHUNK 128
#define NCHUNK 32          // routing chunks (128 rows each)
#define CCHUNK 64          // pack/colsum chunk rows
#define NCHUNK_CS 64       // colsum partial count

// float-offsets in ws
#define WS_WO   0                      // [B][2048] f32
#define WS_SP   65536                  // [B][32][2048] f32 (colsum partials [B][64][128] alias; consumed before routing writes)
#define WS_PACK 2162688                // packed bf16: 16,777,216 ushorts (8M float-slots)
#define WS_TOTAL_F (WS_PACK + 8388608)

typedef __attribute__((ext_vector_type(8))) short bf16x8;
typedef __attribute__((ext_vector_type(4))) float f32x4;

__device__ inline ushort f2bf(float x) {
    unsigned u = __float_as_uint(x);
    u += 0x7FFFu + ((u >> 16) & 1u);   // round-to-nearest-even
    return (ushort)(u >> 16);
}

// ---------------------------------------------------------------------------
// K0: pack u -> bf16 A-fragment tiles + colsum partials. grid (64, B), block 256.
// Packed layout: [b][rowtile(256)][kt(4)][lane(64)][8 bf16];
//   lane = (row&15) | ((klocal>>3)<<4), j = k&7.
__global__ __launch_bounds__(256) void pack_kernel(const float* __restrict__ u,
                                                   float* __restrict__ ws, int do_pack) {
    const int b = blockIdx.y, chunk = blockIdx.x, t = threadIdx.x;
    const int c0 = chunk * CCHUNK;
    ushort* up = (ushort*)(ws + WS_PACK);
    const int k4 = t & 31, rg = t >> 5;
    float4 acc = {0.f, 0.f, 0.f, 0.f};
    #pragma unroll
    for (int m = 0; m < 8; m++) {
        int R = c0 + m * 8 + rg;
        float4 v = *(const float4*)&u[((size_t)b * I_TOT + R) * K_DIM + k4 * 4];
        acc.x += v.x; acc.y += v.y; acc.z += v.z; acc.w += v.w;
        if (do_pack) {
            int k = k4 * 4;
            int kt = k >> 5, lane_hi = (k & 31) >> 3, j0 = k & 7;
            size_t off = (((size_t)(b * 256 + (R >> 4)) * 4 + kt) * 64
                          + (R & 15) + (lane_hi << 4)) * 8 + j0;
            ushort4 w = { f2bf(v.x), f2bf(v.y), f2bf(v.z), f2bf(v.w) };
            *(ushort4*)&up[off] = w;
        }
    }
    __shared__ __align__(16) float4 red[8][32];
    red[rg][k4] = acc;
    __syncthreads();
    if (t < 32) {
        float4 s = red[0][t];
        #pragma unroll
        for (int r = 1; r < 8; r++) {
            float4 v = red[r][t];
            s.x += v.x; s.y += v.y; s.z += v.z; s.w += v.w;
        }
        *(float4*)&ws[WS_SP + ((size_t)(b * NCHUNK_CS + chunk)) * K_DIM + t * 4] = s;
    }
}

// ---------------------------------------------------------------------------
// K2: update. mode 0: o from colsum partials; 1: o from sp, l2norm+w_o; 2: squash->out.
__global__ __launch_bounds__(256) void update_kernel(const float* __restrict__ W,
                                                     float* __restrict__ ws,
                                                     float* __restrict__ out,
                                                     int mode) {
    const int b = blockIdx.x, t = threadIdx.x;
    const int n = t >> 4, d = t & 15;

    __shared__ float src_s[N_CAP][K_DIM + 4];   // row stride 132 (16B-aligned)
    __shared__ float o_s[N_CAP][16];

    if (mode == 0) {
        const float* sp = ws + WS_SP + (size_t)b * NCHUNK_CS * K_DIM;
        int k = t & 127, half = t >> 7;
        float a = 0.f;
        #pragma unroll 8
        for (int c = 0; c < 32; c++) a += sp[(size_t)(half * 32 + c) * K_DIM + k];
        __shared__ float cred[2][128];
        cred[half][k] = a;
        __syncthreads();
        if (t < 128) src_s[0][t] = (cred[0][t] + cred[1][t]) * (1.f / 16.f);
        __syncthreads();
    } else {
        const float4* sp4 = (const float4*)(ws + WS_SP + (size_t)b * NCHUNK * 2048);
        #pragma unroll
        for (int j = 0; j < 2; j++) {
            int f4 = t + j * 256;            // 0..511
            float4 acc = {0.f, 0.f, 0.f, 0.f};
            #pragma unroll 8
            for (int ch = 0; ch < NCHUNK; ch++) {
                float4 v = sp4[(size_t)ch * 512 + f4];
                acc.x += v.x; acc.y += v.y; acc.z += v.z; acc.w += v.w;
            }
            *(float4*)&src_s[f4 >> 5][(f4 & 31) * 4] = acc;
        }
        __syncthreads();
    }

    const float* srow = (mode == 0) ? src_s[0] : src_s[n];
    float o = 0.f;
    #pragma unroll 8
    for (int k = 0; k < K_DIM; k++) o += srow[k] * W[k * 256 + t];

    o_s[n][d] = o;
    __syncthreads();

    if (mode == 2) {
        float ss = 1e-7f;  // EPS
        #pragma unroll
        for (int j = 0; j < 16; j++) { float v = o_s[n][j]; ss += v * v; }
        float scale = sqrtf(ss) / (0.5f + ss);
        out[b * 256 + t] = scale * o;
        return;
    }

    float ss = 0.f;
    #pragma unroll
    for (int j = 0; j < 16; j++) { float v = o_s[n][j]; ss += v * v; }
    float on = o * rsqrtf(fmaxf(ss, 1e-12f));
    __syncthreads();   // done reading src_s; reuse as w_o staging

    for (int k = 0; k < K_DIM; k++) {
        float p = W[k * 256 + t] * on;
        p += __shfl_xor(p, 1); p += __shfl_xor(p, 2);
        p += __shfl_xor(p, 4); p += __shfl_xor(p, 8);
        if (d == 0) src_s[n][k] = p;
    }
    __syncthreads();
    float* wo = ws + WS_WO + (size_t)b * 2048;
    #pragma unroll
    for (int j = 0; j < 8; j++) {
        int idx = t + j * 256;
        wo[idx] = src_s[idx >> 7][idx & 127];
    }
}

// ---------------------------------------------------------------------------
// K3a: MFMA routing pass. grid (32, B), block 256 (4 waves, 2 row-tiles each).
__global__ __launch_bounds__(256) void routing_mfma(const float* __restrict__ u,
                                                    float* __restrict__ ws) {
    const int b = blockIdx.y, chunk = blockIdx.x, t = threadIdx.x;
    const int lane = t & 63, wave = t >> 6;
    const short* up = (const short*)(ws + WS_PACK);

    __shared__ __align__(16) short wo_bf[N_CAP][144];  // pad 144: 288B rows, 16B-aligned
    __shared__ float c_s[RCHUNK][N_CAP];

    const float* wo = ws + WS_WO + (size_t)b * 2048;
    #pragma unroll
    for (int j = 0; j < 8; j++) {
        int idx = t + j * 256;
        wo_bf[idx >> 7][idx & 127] = (short)f2bf(wo[idx]);
    }
    __syncthreads();

    const int cap = lane & 15, hi = lane >> 4;
    bf16x8 bfrag[4];
    #pragma unroll
    for (int kt = 0; kt < 4; kt++)
        bfrag[kt] = *(const bf16x8*)&wo_bf[cap][kt * 32 + hi * 8];

    #pragma unroll
    for (int rr = 0; rr < 2; rr++) {
        const int rt = wave * 2 + rr;              // block-local row-tile 0..7
        const int rt_g = chunk * 8 + rt;           // 0..255 within batch
        f32x4 acc = {0.f, 0.f, 0.f, 0.f};
        const short* abase = up + (((size_t)(b * 256 + rt_g)) * 4) * 512 + lane * 8;
        #pragma unroll
        for (int kt = 0; kt < 4; kt++) {
            bf16x8 a = *(const bf16x8*)(abase + kt * 512);
            acc = __builtin_amdgcn_mfma_f32_16x16x32_bf16(a, bfrag[kt], acc, 0, 0, 0);
        }
        // softmax over caps: D layout col=lane&15 (cap), row=(lane>>4)*4+reg
        #pragma unroll
        for (int r = 0; r < 4; r++) {
            float v = acc[r];
            float mx = v;
            mx = fmaxf(mx, __shfl_xor(mx, 1)); mx = fmaxf(mx, __shfl_xor(mx, 2));
            mx = fmaxf(mx, __shfl_xor(mx, 4)); mx = fmaxf(mx, __shfl_xor(mx, 8));
            float e = __expf(v - mx);
            float sm = e;
            sm += __shfl_xor(sm, 1); sm += __shfl_xor(sm, 2);
            sm += __shfl_xor(sm, 4); sm += __shfl_xor(sm, 8);
            c_s[rt * 16 + hi * 4 + r][cap] = e / sm;
        }
    }
    __syncthreads();

    // phase 2: fp32 k-parallel accumulation (coalesced u reads)
    const int k4 = t & 31, ng = t >> 5;
    float4 a0 = {0.f,0.f,0.f,0.f}, a1 = {0.f,0.f,0.f,0.f};
    const float4* u2 = (const float4*)(u + ((size_t)b * I_TOT + chunk * RCHUNK) * K_DIM) + k4;
    #pragma unroll 8
    for (int i = 0; i < RCHUNK; i++) {
        float4 v = u2[(size_t)i * 32];
        float2 c2 = *(const float2*)&c_s[i][ng * 2];
        a0.x += v.x * c2.x; a0.y += v.y * c2.x; a0.z += v.z * c2.x; a0.w += v.w * c2.x;
        a1.x += v.x * c2.y; a1.y += v.y * c2.y; a1.z += v.z * c2.y; a1.w += v.w * c2.y;
    }
    float* sp = ws + WS_SP + ((size_t)b * NCHUNK + chunk) * 2048;
    *(float4*)&sp[(ng * 2 + 0) * K_DIM + k4 * 4] = a0;
    *(float4*)&sp[(ng * 2 + 1) * K_DIM + k4 * 4] = a1;
}

// ---------------------------------------------------------------------------
// K3b: fp32 fallback routing (R2 structure, known-good) if ws too small.
__global__ __launch_bounds__(256) void routing_fp32(const float* __restrict__ u,
                                                    float* __restrict__ ws) {
    const int b = blockIdx.y, chunk = blockIdx.x, t = threadIdx.x;
    const int i0 = chunk * RCHUNK;

    __shared__ __align__(16) float wo_s[N_CAP][K_DIM];
    __shared__ __align__(16) float c_s[RCHUNK][N_CAP];

    const float* w_o = ws + WS_WO + (size_t)b * 2048;
    #pragma unroll
    for (int j = 0; j < 8; j++) {
        int idx = t + j * 256;
        ((float*)wo_s)[idx] = w_o[idx];
    }
    __syncthreads();

    {
        const int row = t >> 1, h = t & 1;
        const float4* upx = (const float4*)(u + ((size_t)b * I_TOT + i0 + row) * K_DIM + h * 64);
        const float4* wp = (const float4*)&wo_s[0][h * 64];
        float logit[16];
        #pragma unroll
        for (int n = 0; n < 16; n++) logit[n] = 0.f;
        #pragma unroll
        for (int q = 0; q < 16; q++) {
            float4 v = upx[q];
            #pragma unroll
            for (int n = 0; n < 16; n++) {
                float4 w = wp[n * 32 + q];
                logit[n] += v.x * w.x + v.y * w.y + v.z * w.z + v.w * w.w;
            }
        }
        #pragma unroll
        for (int n = 0; n < 16; n++) logit[n] += __shfl_xor(logit[n], 1);
        float m = logit[0];
        #pragma unroll
        for (int n = 1; n < 16; n++) m = fmaxf(m, logit[n]);
        float sum = 0.f;
        #pragma unroll
        for (int n = 0; n < 16; n++) { logit[n] = __expf(logit[n] - m); sum += logit[n]; }
        float inv = 1.f / sum;
        float4* crow = (float4*)&c_s[row][h * 8];
        if (h == 0) {
            crow[0] = make_float4(logit[0]*inv, logit[1]*inv, logit[2]*inv, logit[3]*inv);
            crow[1] = make_float4(logit[4]*inv, logit[5]*inv, logit[6]*inv, logit[7]*inv);
        } else {
            crow[0] = make_float4(logit[8]*inv, logit[9]*inv, logit[10]*inv, logit[11]*inv);
            crow[1] = make_float4(logit[12]*inv, logit[13]*inv, logit[14]*inv, logit[15]*inv);
        }
    }
    __syncthreads();

    const int k4 = t & 31, ng = t >> 5;
    float4 a0 = {0.f,0.f,0.f,0.f}, a1 = {0.f,0.f,0.f,0.f};
    const float4* u2 = (const float4*)(u + ((size_t)b * I_TOT + i0) * K_DIM) + k4;
    #pragma unroll 8
    for (int i = 0; i < RCHUNK; i++) {
        float4 v = u2[(size_t)i * 32];
        float2 c2 = *(const float2*)&c_s[i][ng * 2];
        a0.x += v.x * c2.x; a0.y += v.y * c2.x; a0.z += v.z * c2.x; a0.w += v.w * c2.x;
        a1.x += v.x * c2.y; a1.y += v.y * c2.y; a1.z += v.z * c2.y; a1.w += v.w * c2.y;
    }
    float* sp = ws + WS_SP + ((size_t)b * NCHUNK + chunk) * 2048;
    *(float4*)&sp[(ng * 2 + 0) * K_DIM + k4 * 4] = a0;
    *(float4*)&sp[(ng * 2 + 1) * K_DIM + k4 * 4] = a1;
}

// ---------------------------------------------------------------------------
extern "C" void kernel_launch(void* const* d_in, const int* in_sizes, int n_in,
                              void* d_out, int out_size, void* d_ws, size_t ws_size,
                              hipStream_t stream) {
    const float* u = (const float*)d_in[0];   // (32, 4096, 128) f32
    const float* W = (const float*)d_in[1];   // (128, 256) f32
    float* out = (float*)d_out;               // (32, 16, 16) f32
    float* ws = (float*)d_ws;

    const int big = (ws_size >= (size_t)WS_TOTAL_F * 4) ? 1 : 0;

    pack_kernel<<<dim3(I_TOT / CCHUNK, BATCH), 256, 0, stream>>>(u, ws, big);
    update_kernel<<<BATCH, 256, 0, stream>>>(W, ws, out, 0);

    for (int pass = 0; pass < 3; pass++) {
        if (big) routing_mfma<<<dim3(NCHUNK, BATCH), 256, 0, stream>>>(u, ws);
        else     routing_fp32<<<dim3(NCHUNK, BATCH), 256, 0, stream>>>(u, ws);
        update_kernel<<<BATCH, 256, 0, stream>>>(W, ws, out, pass == 2 ? 2 : 1);
    }
}

// Round 5
// 112.721 us; speedup vs baseline: 3.7423x; 1.9269x over previous
//
#include <hip/hip_runtime.h>

#define BATCH 32
#define I_TOT 4096
#define N_CAP 16
#define K_DIM 128
#define RCHUNK 128
#define NCHUNK 32          // routing chunks (128 rows each)
#define CCHUNK 64          // pack/colsum chunk rows
#define NCHUNK_CS 64       // colsum partial count

// float-offsets in ws
#define WS_WO   0                      // [B][2048] f32
#define WS_SP   65536                  // [B][32][2048] f32 (colsum partials [B][64][128] alias; consumed before routing writes)
#define WS_PACK 2162688                // packed bf16: 16,777,216 ushorts (8M float-slots)
#define WS_TOTAL_F (WS_PACK + 8388608)

typedef __attribute__((ext_vector_type(8))) short bf16x8;
typedef __attribute__((ext_vector_type(4))) float f32x4;

__device__ inline ushort f2bf(float x) {
    unsigned u = __float_as_uint(x);
    u += 0x7FFFu + ((u >> 16) & 1u);   // round-to-nearest-even
    return (ushort)(u >> 16);
}

// ---------------------------------------------------------------------------
// K0: pack u -> bf16 A-fragment tiles + colsum partials. grid (64, B), block 256.
__global__ __launch_bounds__(256) void pack_kernel(const float* __restrict__ u,
                                                   float* __restrict__ ws, int do_pack) {
    const int b = blockIdx.y, chunk = blockIdx.x, t = threadIdx.x;
    const int c0 = chunk * CCHUNK;
    ushort* up = (ushort*)(ws + WS_PACK);
    const int k4 = t & 31, rg = t >> 5;
    float4 acc = {0.f, 0.f, 0.f, 0.f};
    #pragma unroll
    for (int m = 0; m < 8; m++) {
        int R = c0 + m * 8 + rg;
        float4 v = *(const float4*)&u[((size_t)b * I_TOT + R) * K_DIM + k4 * 4];
        acc.x += v.x; acc.y += v.y; acc.z += v.z; acc.w += v.w;
        if (do_pack) {
            int k = k4 * 4;
            int kt = k >> 5, lane_hi = (k & 31) >> 3, j0 = k & 7;
            size_t off = (((size_t)(b * 256 + (R >> 4)) * 4 + kt) * 64
                          + (R & 15) + (lane_hi << 4)) * 8 + j0;
            ushort4 w = { f2bf(v.x), f2bf(v.y), f2bf(v.z), f2bf(v.w) };
            *(ushort4*)&up[off] = w;
        }
    }
    __shared__ __align__(16) float4 red[8][32];
    red[rg][k4] = acc;
    __syncthreads();
    if (t < 32) {
        float4 s = red[0][t];
        #pragma unroll
        for (int r = 1; r < 8; r++) {
            float4 v = red[r][t];
            s.x += v.x; s.y += v.y; s.z += v.z; s.w += v.w;
        }
        *(float4*)&ws[WS_SP + ((size_t)(b * NCHUNK_CS + chunk)) * K_DIM + t * 4] = s;
    }
}

// ---------------------------------------------------------------------------
// K2 v2: per-(capsule,batch) update. grid (N_CAP, BATCH), block 128.
// mode 0: s = colsum/16 (same for all n); 1: s from sp, l2norm + w_o; 2: squash -> out.
__global__ __launch_bounds__(128) void update_kernel(const float* __restrict__ W,
                                                     float* __restrict__ ws,
                                                     float* __restrict__ out,
                                                     int mode) {
    const int n = blockIdx.x, b = blockIdx.y, t = threadIdx.x;

    __shared__ float s_n[K_DIM];
    __shared__ float o_s[N_CAP + 4];

    // ---- phase A: s_n[k] ----
    if (mode == 0) {
        const float* sp = ws + WS_SP + (size_t)b * NCHUNK_CS * K_DIM;
        float a = 0.f;
        #pragma unroll 8
        for (int c = 0; c < NCHUNK_CS; c++) a += sp[(size_t)c * K_DIM + t];
        s_n[t] = a * (1.f / 16.f);
    } else {
        const float* sp = ws + WS_SP + (size_t)b * NCHUNK * 2048 + n * K_DIM;
        float a = 0.f;
        #pragma unroll 8
        for (int c = 0; c < NCHUNK; c++) a += sp[(size_t)c * 2048 + t];
        s_n[t] = a;
    }
    __syncthreads();

    // ---- phase B: o[d] = sum_k s_n[k] * W[k][n*16+d]; t = d*8 + kseg ----
    {
        const int d = t >> 3, kseg = t & 7;
        const int col = n * 16 + d;
        float p = 0.f;
        #pragma unroll
        for (int j = 0; j < 16; j++) {
            int k = kseg * 16 + j;
            p += s_n[k] * W[k * 256 + col];
        }
        p += __shfl_xor(p, 1); p += __shfl_xor(p, 2); p += __shfl_xor(p, 4);
        if (kseg == 0) o_s[d] = p;
    }
    __syncthreads();

    // ---- phase C ----
    float ss = (mode == 2) ? 1e-7f : 0.f;
    #pragma unroll
    for (int d = 0; d < 16; d++) { float v = o_s[d]; ss += v * v; }

    if (mode == 2) {
        if (t < 16) {
            float scale = sqrtf(ss) / (0.5f + ss);
            out[b * 256 + n * 16 + t] = scale * o_s[t];
        }
        return;
    }

    const float inv = rsqrtf(fmaxf(ss, 1e-12f));
    // w_o[b][n][k] = sum_d W[k][n*16+d] * o[d]*inv ; thread t = k
    const float4* wrow = (const float4*)(W + t * 256 + n * 16);
    const float4* o4 = (const float4*)o_s;
    float acc = 0.f;
    #pragma unroll
    for (int q = 0; q < 4; q++) {
        float4 w = wrow[q];
        float4 o = o4[q];
        acc += w.x * o.x + w.y * o.y + w.z * o.z + w.w * o.w;
    }
    ws[WS_WO + (size_t)b * 2048 + n * K_DIM + t] = acc * inv;
}

// ---------------------------------------------------------------------------
// K3a: MFMA routing pass. grid (32, B), block 256 (4 waves, 2 row-tiles each).
__global__ __launch_bounds__(256) void routing_mfma(const float* __restrict__ u,
                                                    float* __restrict__ ws) {
    const int b = blockIdx.y, chunk = blockIdx.x, t = threadIdx.x;
    const int lane = t & 63, wave = t >> 6;
    const short* up = (const short*)(ws + WS_PACK);

    __shared__ __align__(16) short wo_bf[N_CAP][144];
    __shared__ float c_s[RCHUNK][N_CAP];

    const float* wo = ws + WS_WO + (size_t)b * 2048;
    #pragma unroll
    for (int j = 0; j < 8; j++) {
        int idx = t + j * 256;
        wo_bf[idx >> 7][idx & 127] = (short)f2bf(wo[idx]);
    }
    __syncthreads();

    const int cap = lane & 15, hi = lane >> 4;
    bf16x8 bfrag[4];
    #pragma unroll
    for (int kt = 0; kt < 4; kt++)
        bfrag[kt] = *(const bf16x8*)&wo_bf[cap][kt * 32 + hi * 8];

    #pragma unroll
    for (int rr = 0; rr < 2; rr++) {
        const int rt = wave * 2 + rr;
        const int rt_g = chunk * 8 + rt;
        f32x4 acc = {0.f, 0.f, 0.f, 0.f};
        const short* abase = up + (((size_t)(b * 256 + rt_g)) * 4) * 512 + lane * 8;
        #pragma unroll
        for (int kt = 0; kt < 4; kt++) {
            bf16x8 a = *(const bf16x8*)(abase + kt * 512);
            acc = __builtin_amdgcn_mfma_f32_16x16x32_bf16(a, bfrag[kt], acc, 0, 0, 0);
        }
        #pragma unroll
        for (int r = 0; r < 4; r++) {
            float v = acc[r];
            float mx = v;
            mx = fmaxf(mx, __shfl_xor(mx, 1)); mx = fmaxf(mx, __shfl_xor(mx, 2));
            mx = fmaxf(mx, __shfl_xor(mx, 4)); mx = fmaxf(mx, __shfl_xor(mx, 8));
            float e = __expf(v - mx);
            float sm = e;
            sm += __shfl_xor(sm, 1); sm += __shfl_xor(sm, 2);
            sm += __shfl_xor(sm, 4); sm += __shfl_xor(sm, 8);
            c_s[rt * 16 + hi * 4 + r][cap] = e / sm;
        }
    }
    __syncthreads();

    const int k4 = t & 31, ng = t >> 5;
    float4 a0 = {0.f,0.f,0.f,0.f}, a1 = {0.f,0.f,0.f,0.f};
    const float4* u2 = (const float4*)(u + ((size_t)b * I_TOT + chunk * RCHUNK) * K_DIM) + k4;
    #pragma unroll 8
    for (int i = 0; i < RCHUNK; i++) {
        float4 v = u2[(size_t)i * 32];
        float2 c2 = *(const float2*)&c_s[i][ng * 2];
        a0.x += v.x * c2.x; a0.y += v.y * c2.x; a0.z += v.z * c2.x; a0.w += v.w * c2.x;
        a1.x += v.x * c2.y; a1.y += v.y * c2.y; a1.z += v.z * c2.y; a1.w += v.w * c2.y;
    }
    float* sp = ws + WS_SP + ((size_t)b * NCHUNK + chunk) * 2048;
    *(float4*)&sp[(ng * 2 + 0) * K_DIM + k4 * 4] = a0;
    *(float4*)&sp[(ng * 2 + 1) * K_DIM + k4 * 4] = a1;
}

// ---------------------------------------------------------------------------
// K3b: fp32 fallback routing if ws too small for the packed buffer.
__global__ __launch_bounds__(256) void routing_fp32(const float* __restrict__ u,
                                                    float* __restrict__ ws) {
    const int b = blockIdx.y, chunk = blockIdx.x, t = threadIdx.x;
    const int i0 = chunk * RCHUNK;

    __shared__ __align__(16) float wo_s[N_CAP][K_DIM];
    __shared__ __align__(16) float c_s[RCHUNK][N_CAP];

    const float* w_o = ws + WS_WO + (size_t)b * 2048;
    #pragma unroll
    for (int j = 0; j < 8; j++) {
        int idx = t + j * 256;
        ((float*)wo_s)[idx] = w_o[idx];
    }
    __syncthreads();

    {
        const int row = t >> 1, h = t & 1;
        const float4* upx = (const float4*)(u + ((size_t)b * I_TOT + i0 + row) * K_DIM + h * 64);
        const float4* wp = (const float4*)&wo_s[0][h * 64];
        float logit[16];
        #pragma unroll
        for (int n = 0; n < 16; n++) logit[n] = 0.f;
        #pragma unroll
        for (int q = 0; q < 16; q++) {
            float4 v = upx[q];
            #pragma unroll
            for (int n = 0; n < 16; n++) {
                float4 w = wp[n * 32 + q];
                logit[n] += v.x * w.x + v.y * w.y + v.z * w.z + v.w * w.w;
            }
        }
        #pragma unroll
        for (int n = 0; n < 16; n++) logit[n] += __shfl_xor(logit[n], 1);
        float m = logit[0];
        #pragma unroll
        for (int n = 1; n < 16; n++) m = fmaxf(m, logit[n]);
        float sum = 0.f;
        #pragma unroll
        for (int n = 0; n < 16; n++) { logit[n] = __expf(logit[n] - m); sum += logit[n]; }
        float inv = 1.f / sum;
        float4* crow = (float4*)&c_s[row][h * 8];
        if (h == 0) {
            crow[0] = make_float4(logit[0]*inv, logit[1]*inv, logit[2]*inv, logit[3]*inv);
            crow[1] = make_float4(logit[4]*inv, logit[5]*inv, logit[6]*inv, logit[7]*inv);
        } else {
            crow[0] = make_float4(logit[8]*inv, logit[9]*inv, logit[10]*inv, logit[11]*inv);
            crow[1] = make_float4(logit[12]*inv, logit[13]*inv, logit[14]*inv, logit[15]*inv);
        }
    }
    __syncthreads();

    const int k4 = t & 31, ng = t >> 5;
    float4 a0 = {0.f,0.f,0.f,0.f}, a1 = {0.f,0.f,0.f,0.f};
    const float4* u2 = (const float4*)(u + ((size_t)b * I_TOT + i0) * K_DIM) + k4;
    #pragma unroll 8
    for (int i = 0; i < RCHUNK; i++) {
        float4 v = u2[(size_t)i * 32];
        float2 c2 = *(const float2*)&c_s[i][ng * 2];
        a0.x += v.x * c2.x; a0.y += v.y * c2.x; a0.z += v.z * c2.x; a0.w += v.w * c2.x;
        a1.x += v.x * c2.y; a1.y += v.y * c2.y; a1.z += v.z * c2.y; a1.w += v.w * c2.y;
    }
    float* sp = ws + WS_SP + ((size_t)b * NCHUNK + chunk) * 2048;
    *(float4*)&sp[(ng * 2 + 0) * K_DIM + k4 * 4] = a0;
    *(float4*)&sp[(ng * 2 + 1) * K_DIM + k4 * 4] = a1;
}

// ---------------------------------------------------------------------------
extern "C" void kernel_launch(void* const* d_in, const int* in_sizes, int n_in,
                              void* d_out, int out_size, void* d_ws, size_t ws_size,
                              hipStream_t stream) {
    const float* u = (const float*)d_in[0];   // (32, 4096, 128) f32
    const float* W = (const float*)d_in[1];   // (128, 256) f32
    float* out = (float*)d_out;               // (32, 16, 16) f32
    float* ws = (float*)d_ws;

    const int big = (ws_size >= (size_t)WS_TOTAL_F * 4) ? 1 : 0;

    pack_kernel<<<dim3(I_TOT / CCHUNK, BATCH), 256, 0, stream>>>(u, ws, big);
    update_kernel<<<dim3(N_CAP, BATCH), 128, 0, stream>>>(W, ws, out, 0);

    for (int pass = 0; pass < 3; pass++) {
        if (big) routing_mfma<<<dim3(NCHUNK, BATCH), 256, 0, stream>>>(u, ws);
        else     routing_fp32<<<dim3(NCHUNK, BATCH), 256, 0, stream>>>(u, ws);
        update_kernel<<<dim3(N_CAP, BATCH), 128, 0, stream>>>(W, ws, out, pass == 2 ? 2 : 1);
    }
}